// Round 15
// baseline (206.200 us; speedup 1.0000x reference)
//
#include <hip/hip_runtime.h>
#include <math.h>

#define BB  4
#define KK  16
#define MSn 4096
#define NTn 16384
#define GRIDN 16
#define NCELL (GRIDN*GRIDN*GRIDN)   // 4096 cells
#define CAP 10                      // padded candidates per z-run

// Equal-mass bin boundaries: BND[i] = Phi^-1(i/16). Cell i spans
// [BND[i], BND[i+1]). Any monotone table is CORRECT (binning and prune
// bounds use the same table); Phi^-1 makes occupancy ~1 source/cell
// uniformly (sources are N(0,1)^3 -> CDF-transform is uniform).
__device__ __constant__ float BND[17] = {
    -1e30f, -1.534120544f, -1.150349380f, -0.887146559f, -0.674489750f,
    -0.488776411f, -0.318639364f, -0.157310685f, 0.0f, 0.157310685f,
    0.318639364f, 0.488776411f, 0.674489750f, 0.887146559f, 1.150349380f,
    1.534120544f, 1e30f };

__device__ __forceinline__ int bin1(float x) {
    int idx = 0;
#pragma unroll
    for (int i = 1; i <= 15; ++i) idx += (x >= BND[i]) ? 1 : 0;
    return idx;   // 0..15
}

// ---------------- Kernel 1: val + zero hists/counters ----------------
__global__ __launch_bounds__(256) void sgg_val_kernel(
    const float* __restrict__ logits,  // [B,K,MS]
    const float* __restrict__ w,       // [1,K,1]
    const float* __restrict__ bias,    // [1]
    float* __restrict__ val,           // [B,MS]
    unsigned* __restrict__ ghistS,     // [B*NCELL]
    unsigned* __restrict__ ghistT,     // [B*NCELL]
    unsigned* __restrict__ counters)   // [B]
{
    int i = blockIdx.x * 256 + threadIdx.x;   // [0, B*MS) == [0, B*NCELL)
    ghistS[i] = 0u;
    ghistT[i] = 0u;
    if (i < BB) counters[i] = 0u;
    int b = i >> 12;
    int m = i & (MSn - 1);
    const float* base = logits + (size_t)b * KK * MSn + m;

    float x[KK];
    float mx = -INFINITY;
#pragma unroll
    for (int k = 0; k < KK; ++k) {
        x[k] = base[(size_t)k * MSn];
        mx = fmaxf(mx, x[k]);
    }
    float sum = 0.f;
#pragma unroll
    for (int k = 0; k < KK; ++k) {
        x[k] = expf(x[k] - mx);
        sum += x[k];
    }
    float inv = 1.0f / sum;
    float acc = bias[0];
#pragma unroll
    for (int k = 0; k < KK; ++k) {
        acc += w[k] * (x[k] * inv);
    }
    val[i] = 1.0f / (1.0f + expf(-acc));
}

// ---------------- Kernel 2: histogram (sources + targets) ----------------
__global__ __launch_bounds__(256) void sgg_hist_kernel(
    const float* __restrict__ spos,    // [B,3,MS]
    const float* __restrict__ tpos,    // [B,3,NT]
    unsigned* __restrict__ ghistS,
    unsigned* __restrict__ ghistT)
{
    if (blockIdx.x < 64) {
        int i = blockIdx.x * 256 + threadIdx.x;     // [0, B*MS)
        int b = i >> 12, m = i & (MSn - 1);
        const float* sp = spos + (size_t)b * 3 * MSn;
        int cx = bin1(sp[m]), cy = bin1(sp[MSn + m]), cz = bin1(sp[2 * MSn + m]);
        atomicAdd(&ghistS[b * NCELL + ((cx << 8) | (cy << 4) | cz)], 1u);
    } else {
        int i = (blockIdx.x - 64) * 256 + threadIdx.x;  // [0, B*NT)
        int b = i >> 14, n = i & (NTn - 1);
        const float* tp = tpos + (size_t)b * 3 * NTn;
        int cx = bin1(tp[n]), cy = bin1(tp[NTn + n]), cz = bin1(tp[2 * NTn + n]);
        atomicAdd(&ghistT[b * NCELL + ((cx << 8) | (cy << 4) | cz)], 1u);
    }
}

// ---------------- Kernel 3: prefix-scan both tables ----------------
// 8 blocks: b<4 -> source table (writes cellTab start<<13|cnt, hist->cursor),
// b>=4 -> target table (hist->cursor).
__global__ __launch_bounds__(256) void sgg_scan_kernel(
    unsigned* __restrict__ ghistS,
    unsigned* __restrict__ ghistT,
    unsigned* __restrict__ cellTab)    // [B*NCELL]
{
    __shared__ unsigned part[256];
    int blk = blockIdx.x, t = threadIdx.x;
    bool isSrc = blk < BB;
    int batch = isSrc ? blk : blk - BB;
    unsigned* tab = (isSrc ? ghistS : ghistT) + (size_t)batch * NCELL;

    unsigned cnts[16];
    unsigned sum = 0;
#pragma unroll
    for (int r = 0; r < 16; ++r) { cnts[r] = tab[t * 16 + r]; sum += cnts[r]; }
    part[t] = sum;
    __syncthreads();
    for (int s = 1; s < 256; s <<= 1) {
        unsigned v = (t >= s) ? part[t - s] : 0u;
        __syncthreads();
        part[t] += v;
        __syncthreads();
    }
    unsigned run = part[t] - sum;
#pragma unroll
    for (int r = 0; r < 16; ++r) {
        int bin = t * 16 + r;
        if (isSrc) cellTab[(size_t)batch * NCELL + bin] = (run << 13) | cnts[r];
        tab[bin] = run;               // cursor for scatter
        run += cnts[r];
    }
}

// ---------------- Kernel 4: scatter (sources + targets) ----------------
// csrc/tsrt[pos] = (x,y,z,bitcast(orig_index)). Scatter order within a
// cell is non-deterministic but all consumers take order-independent
// lexicographic (key, orig_index) minima.
__global__ __launch_bounds__(256) void sgg_scatter_kernel(
    const float* __restrict__ spos,
    const float* __restrict__ tpos,
    unsigned* __restrict__ ghistS,     // cursors
    unsigned* __restrict__ ghistT,
    float4* __restrict__ csrc,         // [B,MS]
    float4* __restrict__ tsrt)         // [B,NT]
{
    if (blockIdx.x < 64) {
        int i = blockIdx.x * 256 + threadIdx.x;
        int b = i >> 12, m = i & (MSn - 1);
        const float* sp = spos + (size_t)b * 3 * MSn;
        float x = sp[m], y = sp[MSn + m], z = sp[2 * MSn + m];
        int cid = (bin1(x) << 8) | (bin1(y) << 4) | bin1(z);
        unsigned pos = atomicAdd(&ghistS[b * NCELL + cid], 1u);
        csrc[(size_t)b * MSn + pos] = make_float4(x, y, z, __uint_as_float((unsigned)m));
    } else {
        int i = (blockIdx.x - 64) * 256 + threadIdx.x;
        int b = i >> 14, n = i & (NTn - 1);
        const float* tp = tpos + (size_t)b * 3 * NTn;
        float x = tp[n], y = tp[NTn + n], z = tp[2 * NTn + n];
        int cid = (bin1(x) << 8) | (bin1(y) << 4) | bin1(z);
        unsigned pos = atomicAdd(&ghistT[b * NCELL + cid], 1u);
        tsrt[(size_t)b * NTn + pos] = make_float4(x, y, z, __uint_as_float((unsigned)n));
    }
}

// ---------------- Kernel 5: radius-1 cube scan, 2 threads/target ----------
// Padded fixed-trip runs (CAP slots, select-masked) -> fully unrolled, all
// loads independent, no data-dependent loops (R14's latency+divergence).
// Thread pair splits the 9 z-runs (even/odd); u64 shfl_xor(1) combine.
// Reference-exact per candidate:
//   ss  = (s0*s0+s1*s1)+s2*s2 ; dot = (t0*s0+t1*s1)+t2*s2
//   d2  = fma(-2,dot,tt)+ss        (== (tt-(dot+dot))+ss bit-exactly)
// Lexicographic (monotone_key(d2), orig_m) u64 min == jnp.argmin.
// Prune: sources outside the cube lie beyond the nearest cube face
// (x-plane from BND); done iff !overflow && dmin + 2e-3 < db^2.
__global__ __launch_bounds__(256) void sgg_grid_kernel(
    const float4* __restrict__ tsrt,   // [B,NT] sorted targets
    const unsigned* __restrict__ cellTab,
    const float4* __restrict__ csrc,
    const float* __restrict__ val,     // [B,MS]
    float* __restrict__ out,           // [B,NT]
    unsigned* __restrict__ counters,   // [B]
    unsigned short* __restrict__ lists)// [B,NT]
{
    int gid = blockIdx.x * 256 + threadIdx.x;   // [0, 2*B*NT)
    int pairid = gid & 1;
    int n = gid >> 1;                           // sorted slot [0, B*NT)
    int b = n >> 14;
    float4 tq = tsrt[n];
    float t0 = tq.x, t1 = tq.y, t2 = tq.z;
    unsigned ln = __float_as_uint(tq.w);
    float tt = __fadd_rn(__fadd_rn(__fmul_rn(t0, t0), __fmul_rn(t1, t1)),
                         __fmul_rn(t2, t2));

    int tcx = bin1(t0), tcy = bin1(t1), tcz = bin1(t2);
    int zlo = tcz - 1 < 0 ? 0 : tcz - 1;
    int zhi = tcz + 1 > 15 ? 15 : tcz + 1;

    const unsigned* ctab = cellTab + (size_t)b * NCELL;
    const float4* sq = csrc + (size_t)b * MSn;
    unsigned long long best = ~0ull;
    int overflow = 0;

#pragma unroll
    for (int c = 0; c < 9; ++c) {
        if ((c & 1) != pairid) continue;        // runs split across the pair
        int cx = tcx + (c / 3) - 1;
        int cy = tcy + (c % 3) - 1;
        bool ok = ((unsigned)cx <= 15u) && ((unsigned)cy <= 15u);
        int sx = ok ? cx : 0, sy = ok ? cy : 0;
        unsigned c0 = ctab[(sx << 8) | (sy << 4) | zlo];
        unsigned c1 = ctab[(sx << 8) | (sy << 4) | zhi];
        unsigned S = c0 >> 13;
        unsigned E = ok ? ((c1 >> 13) + (c1 & 0x1FFFu)) : S;
        unsigned cnt = E - S;
        overflow |= (cnt > CAP);
#pragma unroll
        for (int u = 0; u < CAP; ++u) {
            float4 f = sq[S + u];               // may overread into tsrt (in-ws, masked)
            bool valid = (u < (int)cnt);
            float ss  = __fadd_rn(__fadd_rn(__fmul_rn(f.x, f.x), __fmul_rn(f.y, f.y)),
                                  __fmul_rn(f.z, f.z));
            float dot = __fadd_rn(__fadd_rn(__fmul_rn(t0, f.x), __fmul_rn(t1, f.y)),
                                  __fmul_rn(t2, f.z));
            float d2  = __fadd_rn(__builtin_fmaf(-2.0f, dot, tt), ss);
            unsigned uu = __float_as_uint(d2);
            unsigned k = uu ^ ((unsigned)((int)uu >> 31) | 0x80000000u);
            unsigned long long pk =
                ((unsigned long long)k << 32) | __float_as_uint(f.w);
            pk = valid ? pk : ~0ull;
            best = pk < best ? pk : best;
        }
    }

    unsigned long long o = __shfl_xor(best, 1, 64);
    best = o < best ? o : best;
    overflow |= __shfl_xor(overflow, 1, 64);

    if (pairid == 0) {
        // cube face distances (BND sentinels +-1e30 make edge faces INF)
        int xlo = tcx - 1 < 0 ? 0 : tcx - 1, xhi = tcx + 1 > 15 ? 15 : tcx + 1;
        int ylo = tcy - 1 < 0 ? 0 : tcy - 1, yhi = tcy + 1 > 15 ? 15 : tcy + 1;
        float db = fminf(fminf(t0 - BND[xlo], BND[xhi + 1] - t0),
                   fminf(fminf(t1 - BND[ylo], BND[yhi + 1] - t1),
                   fminf(t2 - BND[zlo], BND[zhi + 1] - t2)));
        unsigned kmin = (unsigned)(best >> 32);
        unsigned imin = (unsigned)best;
        unsigned uu = (kmin & 0x80000000u) ? (kmin & 0x7FFFFFFFu) : ~kmin;
        float dminf = __uint_as_float(uu);
        bool have = (best != ~0ull);
        bool done = have && !overflow &&
                    (__fadd_rn(dminf, 2e-3f) < __fmul_rn(db, db));
        if (done) {
            out[b * NTn + (int)ln] = val[b * MSn + (int)imin];
        } else {
            unsigned idx = atomicAdd(&counters[b], 1u);
            lists[(size_t)b * NTn + idx] = (unsigned short)ln;
        }
    }
}

// ---------------- Kernel 6: tail — one wave per spilled target -------------
__global__ __launch_bounds__(256) void sgg_tail_kernel(
    const float* __restrict__ tpos,    // [B,3,NT]
    const float4* __restrict__ csrc,   // [B,MS]
    const unsigned* __restrict__ counters,
    const unsigned short* __restrict__ lists,
    const float* __restrict__ val,
    float* __restrict__ out)
{
    int lane = threadIdx.x & 63;
    int wv   = blockIdx.x * 4 + (threadIdx.x >> 6);   // 8192 waves total

    for (int b = 0; b < BB; ++b) {
        unsigned cnt = counters[b];
        const float4* sq = csrc + (size_t)b * MSn;
        const float* tp = tpos + (size_t)b * 3 * NTn;
        for (unsigned i = wv; i < cnt; i += 8192) {
            int ln = lists[(size_t)b * NTn + i];
            float t0 = tp[ln], t1 = tp[NTn + ln], t2 = tp[2 * NTn + ln];
            float tt = __fadd_rn(__fadd_rn(__fmul_rn(t0, t0), __fmul_rn(t1, t1)),
                                 __fmul_rn(t2, t2));
            unsigned long long best = ~0ull;
            for (int r = 0; r < MSn / 64; ++r) {
                float4 f = sq[r * 64 + lane];         // coalesced
                float ss  = __fadd_rn(__fadd_rn(__fmul_rn(f.x, f.x), __fmul_rn(f.y, f.y)),
                                      __fmul_rn(f.z, f.z));
                float dot = __fadd_rn(__fadd_rn(__fmul_rn(t0, f.x), __fmul_rn(t1, f.y)),
                                      __fmul_rn(t2, f.z));
                float d2  = __fadd_rn(__builtin_fmaf(-2.0f, dot, tt), ss);
                unsigned u = __float_as_uint(d2);
                unsigned k = u ^ ((unsigned)((int)u >> 31) | 0x80000000u);
                unsigned long long pk =
                    ((unsigned long long)k << 32) | __float_as_uint(f.w);
                best = pk < best ? pk : best;
            }
#pragma unroll
            for (int s = 1; s < 64; s <<= 1) {
                unsigned long long o = __shfl_xor(best, s, 64);
                best = o < best ? o : best;
            }
            if (lane == 0)
                out[b * NTn + ln] = val[b * MSn + (unsigned)(best & 0xFFFFFFFFu)];
        }
    }
}

extern "C" void kernel_launch(void* const* d_in, const int* in_sizes, int n_in,
                              void* d_out, int out_size, void* d_ws, size_t ws_size,
                              hipStream_t stream) {
    const float* sem  = (const float*)d_in[0];  // [4,16,4096]
    const float* spos = (const float*)d_in[1];  // [4,3,4096]
    const float* tpos = (const float*)d_in[2];  // [4,3,16384]
    const float* w    = (const float*)d_in[3];  // [1,16,1]
    const float* bias = (const float*)d_in[4];  // [1]
    float* out = (float*)d_out;                 // [4,1,16384]

    char* p = (char*)d_ws;
    float*          val     = (float*)p;          p += (size_t)BB * MSn * 4;    // 64 KB
    unsigned*       cellTab = (unsigned*)p;       p += (size_t)BB * NCELL * 4;  // 64 KB
    float4*         csrc    = (float4*)p;         p += (size_t)BB * MSn * 16;   // 256 KB
    float4*         tsrt    = (float4*)p;         p += (size_t)BB * NTn * 16;   // 1 MB
    // lists (used by K5/K6) overlays ghistS/ghistT (dead after K4) — 128 KB
    unsigned short* lists   = (unsigned short*)p;
    unsigned*       ghistS  = (unsigned*)p;       p += (size_t)BB * NCELL * 4;  // 64 KB
    unsigned*       ghistT  = (unsigned*)p;       p += (size_t)BB * NCELL * 4;  // 64 KB
    unsigned*       counters= (unsigned*)p;                                     // 16 B

    sgg_val_kernel<<<64, 256, 0, stream>>>(sem, w, bias, val, ghistS, ghistT, counters);
    sgg_hist_kernel<<<320, 256, 0, stream>>>(spos, tpos, ghistS, ghistT);
    sgg_scan_kernel<<<8, 256, 0, stream>>>(ghistS, ghistT, cellTab);
    sgg_scatter_kernel<<<320, 256, 0, stream>>>(spos, tpos, ghistS, ghistT, csrc, tsrt);
    sgg_grid_kernel<<<(2 * BB * NTn) / 256, 256, 0, stream>>>(tsrt, cellTab, csrc, val, out,
                                                              counters, lists);
    sgg_tail_kernel<<<2048, 256, 0, stream>>>(tpos, csrc, counters, lists, val, out);
}

// Round 16
// 84.083 us; speedup vs baseline: 2.4523x; 2.4523x over previous
//
#include <hip/hip_runtime.h>
#include <math.h>

#define BB  4
#define KK  16
#define MSn 4096
#define NTn 16384
#define NCELL 4096
#define CW 0.45f
#define CO (-3.6f)

__device__ __forceinline__ int bin1u(float x) {
    int c = (int)floorf((x - CO) / CW);
    return c < 0 ? 0 : (c > 15 ? 15 : c);
}

// ---------------- Kernel 1: val + init (ghists, keys, counters) -------------
__global__ __launch_bounds__(256) void sgg_val_kernel(
    const float* __restrict__ logits,  // [B,K,MS]
    const float* __restrict__ w,       // [1,K,1]
    const float* __restrict__ bias,    // [1]
    float* __restrict__ val,           // [B,MS]
    unsigned* __restrict__ ghistS,     // [B*NCELL]
    unsigned* __restrict__ ghistT,     // [B*NCELL]
    unsigned long long* __restrict__ keys,  // [B*NT]
    unsigned* __restrict__ counters)   // [B]
{
    int i = blockIdx.x * 256 + threadIdx.x;   // [0,16384)
    ghistS[i] = 0u;
    ghistT[i] = 0u;
    unsigned long long* kp = keys + (size_t)i * 4;
    kp[0] = ~0ull; kp[1] = ~0ull; kp[2] = ~0ull; kp[3] = ~0ull;
    if (i < BB) counters[i] = 0u;

    int b = i >> 12;
    int m = i & (MSn - 1);
    const float* base = logits + (size_t)b * KK * MSn + m;
    float x[KK];
    float mx = -INFINITY;
#pragma unroll
    for (int k = 0; k < KK; ++k) {
        x[k] = base[(size_t)k * MSn];
        mx = fmaxf(mx, x[k]);
    }
    float sum = 0.f;
#pragma unroll
    for (int k = 0; k < KK; ++k) {
        x[k] = expf(x[k] - mx);
        sum += x[k];
    }
    float inv = 1.0f / sum;
    float acc = bias[0];
#pragma unroll
    for (int k = 0; k < KK; ++k) {
        acc += w[k] * (x[k] * inv);
    }
    val[i] = 1.0f / (1.0f + expf(-acc));
}

// ---------------- Kernel 2: histogram (sources + targets) ----------------
__global__ __launch_bounds__(256) void sgg_hist_kernel(
    const float* __restrict__ spos, const float* __restrict__ tpos,
    unsigned* __restrict__ ghistS, unsigned* __restrict__ ghistT)
{
    if (blockIdx.x < 64) {
        int i = blockIdx.x * 256 + threadIdx.x;     // [0, B*MS)
        int b = i >> 12, m = i & (MSn - 1);
        const float* sp = spos + (size_t)b * 3 * MSn;
        int cx = bin1u(sp[m]), cy = bin1u(sp[MSn + m]), cz = bin1u(sp[2 * MSn + m]);
        atomicAdd(&ghistS[b * NCELL + ((cx << 8) | (cy << 4) | cz)], 1u);
    } else {
        int i = (blockIdx.x - 64) * 256 + threadIdx.x;  // [0, B*NT)
        int b = i >> 14, n = i & (NTn - 1);
        const float* tp = tpos + (size_t)b * 3 * NTn;
        int cx = bin1u(tp[n]), cy = bin1u(tp[NTn + n]), cz = bin1u(tp[2 * NTn + n]);
        atomicAdd(&ghistT[b * NCELL + ((cx << 8) | (cy << 4) | cz)], 1u);
    }
}

// ---------------- Kernel 3: prefix-scan both tables ----------------
__global__ __launch_bounds__(256) void sgg_scan_kernel(
    unsigned* __restrict__ ghistS, unsigned* __restrict__ ghistT,
    unsigned* __restrict__ cellTab)
{
    __shared__ unsigned part[256];
    int blk = blockIdx.x, t = threadIdx.x;
    bool isSrc = blk < BB;
    int batch = isSrc ? blk : blk - BB;
    unsigned* tab = (isSrc ? ghistS : ghistT) + (size_t)batch * NCELL;

    unsigned cnts[16];
    unsigned sum = 0;
#pragma unroll
    for (int r = 0; r < 16; ++r) { cnts[r] = tab[t * 16 + r]; sum += cnts[r]; }
    part[t] = sum;
    __syncthreads();
    for (int s = 1; s < 256; s <<= 1) {
        unsigned v = (t >= s) ? part[t - s] : 0u;
        __syncthreads();
        part[t] += v;
        __syncthreads();
    }
    unsigned run = part[t] - sum;
#pragma unroll
    for (int r = 0; r < 16; ++r) {
        int bin = t * 16 + r;
        if (isSrc) cellTab[(size_t)batch * NCELL + bin] = (run << 13) | cnts[r];
        tab[bin] = run;               // cursor for scatter
        run += cnts[r];
    }
}

// ---------------- Kernel 4: scatter (sources + targets) ----------------
__global__ __launch_bounds__(256) void sgg_scatter_kernel(
    const float* __restrict__ spos, const float* __restrict__ tpos,
    unsigned* __restrict__ ghistS, unsigned* __restrict__ ghistT,
    float4* __restrict__ csrc, float4* __restrict__ tsrt)
{
    if (blockIdx.x < 64) {
        int i = blockIdx.x * 256 + threadIdx.x;
        int b = i >> 12, m = i & (MSn - 1);
        const float* sp = spos + (size_t)b * 3 * MSn;
        float x = sp[m], y = sp[MSn + m], z = sp[2 * MSn + m];
        int cid = (bin1u(x) << 8) | (bin1u(y) << 4) | bin1u(z);
        unsigned pos = atomicAdd(&ghistS[b * NCELL + cid], 1u);
        csrc[(size_t)b * MSn + pos] = make_float4(x, y, z, __uint_as_float((unsigned)m));
    } else {
        int i = (blockIdx.x - 64) * 256 + threadIdx.x;
        int b = i >> 14, n = i & (NTn - 1);
        const float* tp = tpos + (size_t)b * 3 * NTn;
        float x = tp[n], y = tp[NTn + n], z = tp[2 * NTn + n];
        int cid = (bin1u(x) << 8) | (bin1u(y) << 4) | bin1u(z);
        unsigned pos = atomicAdd(&ghistT[b * NCELL + cid], 1u);
        tsrt[(size_t)b * NTn + pos] = make_float4(x, y, z, __uint_as_float((unsigned)n));
    }
}

// ---------------- Kernel 5: 27-cell scan, 8 wave-uniform subsets ----------
// sub = blockIdx.x & 7 is BLOCK-uniform -> uniform branches, full 64-lane
// coherence (sorted targets). Each subset scans 3-4 of the 27 cells and
// merges via atomicMin on the per-target key (distinct addresses).
// Reference-exact per candidate:
//   ss  = (s0*s0+s1*s1)+s2*s2 ; dot = (t0*s0+t1*s1)+t2*s2
//   d2  = fma(-2,dot,tt)+ss       (== (tt-(dot+dot))+ss bit-exactly)
// u64 lexicographic (monotone_key(d2), orig_m) min == jnp.argmin.
__global__ __launch_bounds__(256) void sgg_scan8_kernel(
    const float4* __restrict__ tsrt,   // [B,NT] sorted targets
    const unsigned* __restrict__ cellTab,
    const float4* __restrict__ csrc,
    unsigned long long* __restrict__ keys)  // [B*NT] by sorted slot
{
    int sub = blockIdx.x & 7;                       // cell-subset (uniform)
    int n   = (blockIdx.x >> 3) * 256 + threadIdx.x;  // sorted slot
    int b   = n >> 14;
    float4 tq = tsrt[n];
    float t0 = tq.x, t1 = tq.y, t2 = tq.z;
    float tt = __fadd_rn(__fadd_rn(__fmul_rn(t0, t0), __fmul_rn(t1, t1)),
                         __fmul_rn(t2, t2));
    int tcx = bin1u(t0), tcy = bin1u(t1), tcz = bin1u(t2);

    const unsigned* ctab = cellTab + (size_t)b * NCELL;
    const float4* sq = csrc + (size_t)b * MSn;
    unsigned long long best = ~0ull;

#pragma unroll
    for (int c = 0; c < 27; ++c) {
        if ((c & 7) != sub) continue;               // compile/block-uniform
        int cx = tcx + (c / 9) - 1;
        int cy = tcy + ((c / 3) % 3) - 1;
        int cz = tcz + (c % 3) - 1;
        if ((unsigned)cx > 15u || (unsigned)cy > 15u || (unsigned)cz > 15u)
            continue;
        unsigned ct = ctab[(cx << 8) | (cy << 4) | cz];
        unsigned S = ct >> 13, cnt = ct & 0x1FFFu;
        for (unsigned i = 0; i < cnt; ++i) {
            float4 f = sq[S + i];
            float ss  = __fadd_rn(__fadd_rn(__fmul_rn(f.x, f.x), __fmul_rn(f.y, f.y)),
                                  __fmul_rn(f.z, f.z));
            float dot = __fadd_rn(__fadd_rn(__fmul_rn(t0, f.x), __fmul_rn(t1, f.y)),
                                  __fmul_rn(t2, f.z));
            float d2  = __fadd_rn(__builtin_fmaf(-2.0f, dot, tt), ss);
            unsigned u = __float_as_uint(d2);
            unsigned k = (u & 0x80000000u) ? ~u : (u | 0x80000000u);
            unsigned long long pk =
                ((unsigned long long)k << 32) | __float_as_uint(f.w);
            best = pk < best ? pk : best;
        }
    }
    if (best != ~0ull) atomicMin(&keys[n], best);
}

// ---------------- Kernel 6: resolve — prune-or-spill ----------------
// done iff dmin + 2e-3 < db^2 (faces with real cells beyond them only;
// clamped edge cells inside the cube already contain everything on that
// side — proven R13/R14, absmax 0). Spill via wave-aggregated atomic
// (one atomicAdd per wave; kills R15's same-address serialization).
__global__ __launch_bounds__(256) void sgg_resolve_kernel(
    const float4* __restrict__ tsrt,
    const unsigned long long* __restrict__ keys,
    const float* __restrict__ val,
    float* __restrict__ out,
    unsigned* __restrict__ counters,
    unsigned short* __restrict__ lists)
{
    int n = blockIdx.x * 256 + threadIdx.x;   // sorted slot
    int b = n >> 14;
    float4 tq = tsrt[n];
    float t0 = tq.x, t1 = tq.y, t2 = tq.z;
    unsigned ln = __float_as_uint(tq.w);
    int tcx = bin1u(t0), tcy = bin1u(t1), tcz = bin1u(t2);

    unsigned long long best = keys[n];
    unsigned kmin = (unsigned)(best >> 32);
    unsigned uu = (kmin & 0x80000000u) ? (kmin & 0x7FFFFFFFu) : ~kmin;
    float dminf = __uint_as_float(uu);

    float db = 1e30f;
    if (tcx >= 2)  db = fminf(db, t0 - (CO + (float)(tcx - 1) * CW));
    if (tcx <= 13) db = fminf(db, (CO + (float)(tcx + 2) * CW) - t0);
    if (tcy >= 2)  db = fminf(db, t1 - (CO + (float)(tcy - 1) * CW));
    if (tcy <= 13) db = fminf(db, (CO + (float)(tcy + 2) * CW) - t1);
    if (tcz >= 2)  db = fminf(db, t2 - (CO + (float)(tcz - 1) * CW));
    if (tcz <= 13) db = fminf(db, (CO + (float)(tcz + 2) * CW) - t2);

    bool have = (best != ~0ull);
    bool done = have && (db > 9e29f ||
                         __fadd_rn(dminf, 2e-3f) < __fmul_rn(db, db));
    if (done)
        out[b * NTn + (int)ln] = val[b * MSn + (int)(unsigned)best];

    bool spill = !done;
    unsigned long long mask = __ballot(spill);
    if (spill) {
        unsigned lane = threadIdx.x & 63u;
        int lead = __ffsll((unsigned long long)mask) - 1;
        unsigned rank = (unsigned)__popcll(mask & ((1ull << lane) - 1ull));
        unsigned base = 0;
        if ((int)lane == lead)
            base = atomicAdd(&counters[b], (unsigned)__popcll(mask));
        base = __shfl(base, lead, 64);
        lists[(size_t)b * NTn + base + rank] = (unsigned short)ln;
    }
}

// ---------------- Kernel 7: tail — one wave per spilled target -------------
__global__ __launch_bounds__(256) void sgg_tail_kernel(
    const float* __restrict__ tpos,    // [B,3,NT]
    const float4* __restrict__ csrc,   // [B,MS]
    const unsigned* __restrict__ counters,
    const unsigned short* __restrict__ lists,
    const float* __restrict__ val,
    float* __restrict__ out)
{
    int lane = threadIdx.x & 63;
    int wv   = blockIdx.x * 4 + (threadIdx.x >> 6);   // 8192 waves total

    for (int b = 0; b < BB; ++b) {
        unsigned cnt = counters[b];
        const float4* sq = csrc + (size_t)b * MSn;
        const float* tp = tpos + (size_t)b * 3 * NTn;
        for (unsigned i = wv; i < cnt; i += 8192) {
            int ln = lists[(size_t)b * NTn + i];
            float t0 = tp[ln], t1 = tp[NTn + ln], t2 = tp[2 * NTn + ln];
            float tt = __fadd_rn(__fadd_rn(__fmul_rn(t0, t0), __fmul_rn(t1, t1)),
                                 __fmul_rn(t2, t2));
            unsigned long long best = ~0ull;
            for (int r = 0; r < MSn / 64; ++r) {
                float4 f = sq[r * 64 + lane];         // coalesced
                float ss  = __fadd_rn(__fadd_rn(__fmul_rn(f.x, f.x), __fmul_rn(f.y, f.y)),
                                      __fmul_rn(f.z, f.z));
                float dot = __fadd_rn(__fadd_rn(__fmul_rn(t0, f.x), __fmul_rn(t1, f.y)),
                                      __fmul_rn(t2, f.z));
                float d2  = __fadd_rn(__builtin_fmaf(-2.0f, dot, tt), ss);
                unsigned u = __float_as_uint(d2);
                unsigned k = (u & 0x80000000u) ? ~u : (u | 0x80000000u);
                unsigned long long pk =
                    ((unsigned long long)k << 32) | __float_as_uint(f.w);
                best = pk < best ? pk : best;
            }
#pragma unroll
            for (int s = 1; s < 64; s <<= 1) {
                unsigned long long o = __shfl_xor(best, s, 64);
                best = o < best ? o : best;
            }
            if (lane == 0)
                out[b * NTn + ln] = val[b * MSn + (unsigned)(best & 0xFFFFFFFFu)];
        }
    }
}

extern "C" void kernel_launch(void* const* d_in, const int* in_sizes, int n_in,
                              void* d_out, int out_size, void* d_ws, size_t ws_size,
                              hipStream_t stream) {
    const float* sem  = (const float*)d_in[0];  // [4,16,4096]
    const float* spos = (const float*)d_in[1];  // [4,3,4096]
    const float* tpos = (const float*)d_in[2];  // [4,3,16384]
    const float* w    = (const float*)d_in[3];  // [1,16,1]
    const float* bias = (const float*)d_in[4];  // [1]
    float* out = (float*)d_out;                 // [4,1,16384]

    char* p = (char*)d_ws;
    float*              val     = (float*)p;     p += (size_t)BB * MSn * 4;    // 64 KB
    unsigned*           cellTab = (unsigned*)p;  p += (size_t)BB * NCELL * 4;  // 64 KB
    float4*             csrc    = (float4*)p;    p += (size_t)BB * MSn * 16;   // 256 KB
    float4*             tsrt    = (float4*)p;    p += (size_t)BB * NTn * 16;   // 1 MB
    unsigned long long* keys    = (unsigned long long*)p;
                                                 p += (size_t)BB * NTn * 8;    // 512 KB
    // lists (K6/K7) overlays ghistS/ghistT (dead after K4) — 128 KB
    unsigned short*     lists   = (unsigned short*)p;
    unsigned*           ghistS  = (unsigned*)p;  p += (size_t)BB * NCELL * 4;  // 64 KB
    unsigned*           ghistT  = (unsigned*)p;  p += (size_t)BB * NCELL * 4;  // 64 KB
    unsigned*           counters= (unsigned*)p;                                // 16 B

    sgg_val_kernel<<<64, 256, 0, stream>>>(sem, w, bias, val, ghistS, ghistT, keys, counters);
    sgg_hist_kernel<<<320, 256, 0, stream>>>(spos, tpos, ghistS, ghistT);
    sgg_scan_kernel<<<8, 256, 0, stream>>>(ghistS, ghistT, cellTab);
    sgg_scatter_kernel<<<320, 256, 0, stream>>>(spos, tpos, ghistS, ghistT, csrc, tsrt);
    sgg_scan8_kernel<<<(BB * NTn / 256) * 8, 256, 0, stream>>>(tsrt, cellTab, csrc, keys);
    sgg_resolve_kernel<<<(BB * NTn) / 256, 256, 0, stream>>>(tsrt, keys, val, out,
                                                             counters, lists);
    sgg_tail_kernel<<<2048, 256, 0, stream>>>(tpos, csrc, counters, lists, val, out);
}